// Round 20
// baseline (494.870 us; speedup 1.0000x reference)
//
#include <hip/hip_runtime.h>
#include <hip/hip_bf16.h>
#include <math.h>

#define NN   20000
#define NE   200000
#define NG   128
#define EMBD 256
#define NL   4
#define RBFD 10
#define TBINS 512       // nearest-neighbor bins over d in [0,8]; rows = TBINS+1
#define PAIRW 5000      // dual-stream waves in k_agg (1250 blocks x 4)
#define GSPL 8

typedef __attribute__((ext_vector_type(8))) short bf16x8;
typedef __attribute__((ext_vector_type(4))) float f32x4;

__device__ __forceinline__ f32x4 up4(uint2 u) {
  f32x4 r;
  r.x = __uint_as_float(u.x << 16);
  r.y = __uint_as_float(u.x & 0xffff0000u);
  r.z = __uint_as_float(u.y << 16);
  r.w = __uint_as_float(u.y & 0xffff0000u);
  return r;
}

__device__ __forceinline__ void gload16(const void* g, void* l) {
  __builtin_amdgcn_global_load_lds(
      (const __attribute__((address_space(1))) void*)g,
      (__attribute__((address_space(3))) void*)l, 16, 0, 0);
}

__device__ __forceinline__ unsigned short bfbits(float v) {
  __hip_bfloat16 h = __float2bfloat16(v);
  return *(unsigned short*)&h;
}

// ---------------- prep kernels ----------------

__global__ void k_embed(const int* __restrict__ x, const float* __restrict__ emb,
                        float* __restrict__ xn, __hip_bfloat16* __restrict__ xnb) {
  int idx = blockIdx.x * blockDim.x + threadIdx.x;   // float4 index
  if (idx >= NN * (EMBD / 4)) return;
  int n  = idx >> 6;
  int c4 = (idx & 63) << 2;
  float4 v = *(const float4*)(emb + (size_t)x[n] * EMBD + c4);
  *(float4*)(xn + (size_t)n * EMBD + c4) = v;
  __hip_bfloat16* xb = xnb + (size_t)n * EMBD + c4;
  xb[0] = __float2bfloat16(v.x); xb[1] = __float2bfloat16(v.y);
  xb[2] = __float2bfloat16(v.z); xb[3] = __float2bfloat16(v.w);
}

// weff[l][gf][k][c] = (We @ W*_e[l])[k][c];  beff[l][gf][c] = be @ W*_e[l] + b*[l]
__global__ void k_wsmall(const float* __restrict__ We, const float* __restrict__ be,
                         const float* __restrict__ Wge, const float* __restrict__ bg,
                         const float* __restrict__ Wfe, const float* __restrict__ bf,
                         float* __restrict__ weff, float* __restrict__ beff) {
  int tid = blockIdx.x * blockDim.x + threadIdx.x;
  const int WPER = RBFD * EMBD;   // 2560
  if (tid < NL * 2 * WPER) {
    int l  = tid / (2 * WPER);
    int r  = tid % (2 * WPER);
    int gf = r / WPER;
    int r2 = r % WPER;
    int k = r2 / EMBD, c = r2 % EMBD;
    const float* W = (gf == 0 ? Wge : Wfe) + (size_t)l * EMBD * EMBD;
    float s = 0.f;
    for (int j = 0; j < EMBD; ++j) s += We[k * EMBD + j] * W[(size_t)j * EMBD + c];
    weff[tid] = s;
  } else {
    int t2 = tid - NL * 2 * WPER;
    if (t2 >= NL * 2 * EMBD) return;
    int l  = t2 / (2 * EMBD);
    int r  = t2 % (2 * EMBD);
    int gf = r / EMBD, c = r % EMBD;
    const float* W = (gf == 0 ? Wge : Wfe) + (size_t)l * EMBD * EMBD;
    const float* b = (gf == 0 ? bg : bf) + (size_t)l * EMBD;
    float s = b[c];
    for (int j = 0; j < EMBD; ++j) s += be[j] * W[(size_t)j * EMBD + c];
    beff[t2] = s;
  }
}

// tbl[l][bin][t] (bf16): t<256 -> zg contribution, t>=256 -> zf; bias folded in
__global__ void k_table(const float* __restrict__ weff, const float* __restrict__ beff,
                        __hip_bfloat16* __restrict__ tbl) {
  int idx = blockIdx.x * blockDim.x + threadIdx.x;
  if (idx >= NL * (TBINS + 1) * 512) return;
  int l = idx / ((TBINS + 1) * 512);
  int r = idx % ((TBINS + 1) * 512);
  int bin = r >> 9;
  int t = r & 511;
  int gf = t >> 8, c = t & 255;
  float d = (float)bin * (8.0f / (float)TBINS);
  const float* w = weff + ((size_t)(l * 2 + gf) * RBFD) * EMBD + c;
  float s = beff[(size_t)(l * 2 + gf) * EMBD + c];
  const float width = 8.0f / 9.0f;
  #pragma unroll
  for (int k = 0; k < RBFD; ++k) {
    float u = (d - (float)k * width) / width;
    s += __expf(-u * u) * w[(size_t)k * EMBD];
  }
  tbl[idx] = __float2bfloat16(s);
}

// WT[l][q][c][k] = W_q[l][k][c] as bf16 (transposed, K-contiguous)
__global__ __launch_bounds__(256) void k_wprep(
    const float* __restrict__ Wgx, const float* __restrict__ Wfx,
    const float* __restrict__ Wgn, const float* __restrict__ Wfn,
    __hip_bfloat16* __restrict__ WT) {
  __shared__ float T[64][65];
  int lq = blockIdx.x; int l = lq >> 2, q = lq & 3;
  const float* W = (q == 0 ? Wgx : q == 1 ? Wfx : q == 2 ? Wgn : Wfn) + (size_t)l * 65536;
  int t = blockIdx.y;
  int k0 = (t & 3) * 64, c0 = (t >> 2) * 64;
  #pragma unroll
  for (int i = 0; i < 16; ++i) {
    int idx = threadIdx.x + i * 256;
    int r = idx >> 6, c = idx & 63;
    T[r][c] = W[(size_t)(k0 + r) * 256 + c0 + c];
  }
  __syncthreads();
  __hip_bfloat16* out = WT + ((size_t)lq * 256) * 256;
  #pragma unroll
  for (int i = 0; i < 16; ++i) {
    int idx = threadIdx.x + i * 256;
    int r = idx >> 6, c = idx & 63;
    out[(size_t)(c0 + r) * 256 + k0 + c] = __float2bfloat16(T[c][r]);
  }
}

// ---------------- CSR build ----------------

__global__ void k_hist(const int* __restrict__ dst, int* __restrict__ cnt) {
  int e = blockIdx.x * blockDim.x + threadIdx.x;
  if (e >= NE) return;
  atomicAdd(&cnt[dst[e]], 1);
}

__global__ __launch_bounds__(1024) void k_scan(const int* __restrict__ cnt,
                                               int* __restrict__ roff,
                                               int* __restrict__ cursor) {
  __shared__ int part[1024];
  const int t = threadIdx.x;
  const int CH = 20;
  int base = t * CH;
  int loc[CH];
  int s = 0;
  #pragma unroll
  for (int i = 0; i < CH; ++i) {
    int idx = base + i;
    int v = (idx < NN) ? cnt[idx] : 0;
    loc[i] = s;
    s += v;
  }
  part[t] = s;
  __syncthreads();
  for (int off = 1; off < 1024; off <<= 1) {
    int v = (t >= off) ? part[t - off] : 0;
    __syncthreads();
    part[t] += v;
    __syncthreads();
  }
  int chunkbase = (t == 0) ? 0 : part[t - 1];
  #pragma unroll
  for (int i = 0; i < CH; ++i) {
    int idx = base + i;
    if (idx < NN) {
      int v = chunkbase + loc[i];
      roff[idx] = v;
      cursor[idx] = v;
    }
  }
  if (t == 1023) roff[NN] = part[1023];
}

// scatter edges dst-sorted; store src and table-row element offset (bin<<9)
__global__ void k_scatter(const int* __restrict__ src, const int* __restrict__ dst,
                          const float* __restrict__ edist,
                          int* __restrict__ cursor,
                          int* __restrict__ src_s, int* __restrict__ bin_s) {
  int e = blockIdx.x * blockDim.x + threadIdx.x;
  if (e >= NE) return;
  int d = dst[e];
  int p = atomicAdd(&cursor[d], 1);
  src_s[p] = src[e];
  int bin = (int)(edist[e] * ((float)TBINS / 8.0f) + 0.5f);
  bin = bin < 0 ? 0 : (bin > TBINS ? TBINS : bin);
  bin_s[p] = bin << 9;
}

// ---------------- per-layer kernels ----------------

// Yb(20000 x 1024, bf16) = xnb @ [Wg_x | Wf_x | Wg_n | Wf_n]  (bf16 MFMA)
// LDS-staged (global_load_lds 16B, swizzled), BK=64, swapped-operand MFMA
__global__ __launch_bounds__(256) void k_nodemm(
    const __hip_bfloat16* __restrict__ xnb, const __hip_bfloat16* __restrict__ WTl,
    __hip_bfloat16* __restrict__ Yb) {
  __shared__ unsigned short As[128 * 64];
  __shared__ unsigned short Bs[128 * 64];
  const int tid = threadIdx.x;
  const int lane = tid & 63;
  const int wave = tid >> 6;
  const int row0 = blockIdx.x << 7;
  const int col0 = blockIdx.y << 7;
  const int q = col0 >> 8;
  const int cb = col0 & 255;
  const unsigned short* xb = (const unsigned short*)xnb;
  const unsigned short* Wb = (const unsigned short*)WTl + ((size_t)q * 256 + cb) * 256;
  const int wnode = (wave >> 1) << 6;
  const int wch   = (wave & 1) << 6;
  f32x4 acc[4][4] = {};

  const int rd0 = (wave << 3) + (lane >> 3);
  const int cd  = lane & 7;

  for (int k0 = 0; k0 < 256; k0 += 64) {
    #pragma unroll
    for (int j = 0; j < 4; ++j) {
      int rd = rd0 + j * 32;
      int cs = cd ^ (rd & 7);
      int ga = row0 + rd; if (ga > NN - 1) ga = NN - 1;
      gload16(xb + (size_t)ga * 256 + k0 + cs * 8,
              (char*)As + (size_t)(j * 256 + wave * 64) * 16);
      gload16(Wb + (size_t)rd * 256 + k0 + cs * 8,
              (char*)Bs + (size_t)(j * 256 + wave * 64) * 16);
    }
    __syncthreads();
    const int rsel = lane & 15, ksl = lane >> 4;
    #pragma unroll
    for (int h = 0; h < 2; ++h) {
      const int c = h * 4 + ksl;
      bf16x8 xa[4], wf[4];
      #pragma unroll
      for (int nn = 0; nn < 4; ++nn) {
        int r = wnode + nn * 16 + rsel;
        xa[nn] = *(const bf16x8*)(&As[r * 64 + (c ^ (r & 7)) * 8]);
      }
      #pragma unroll
      for (int mc = 0; mc < 4; ++mc) {
        int r = wch + mc * 16 + rsel;
        wf[mc] = *(const bf16x8*)(&Bs[r * 64 + (c ^ (r & 7)) * 8]);
      }
      #pragma unroll
      for (int mc = 0; mc < 4; ++mc)
        #pragma unroll
        for (int nn = 0; nn < 4; ++nn)
          acc[mc][nn] = __builtin_amdgcn_mfma_f32_16x16x32_bf16(wf[mc], xa[nn], acc[mc][nn], 0, 0, 0);
    }
    __syncthreads();
  }

  const int nodesel = lane & 15;
  const int chq = (lane >> 4) << 2;
  #pragma unroll
  for (int mc = 0; mc < 4; ++mc) {
    #pragma unroll
    for (int nn = 0; nn < 4; ++nn) {
      int node = row0 + wnode + nn * 16 + nodesel;
      if (node < NN) {
        int ch = col0 + wch + mc * 16 + chq;
        ushort4 pk;
        pk.x = bfbits(acc[mc][nn][0]);
        pk.y = bfbits(acc[mc][nn][1]);
        pk.z = bfbits(acc[mc][nn][2]);
        pk.w = bfbits(acc[mc][nn][3]);
        *(ushort4*)((unsigned short*)Yb + (size_t)node * 1024 + ch) = pk;
      }
    }
  }
}

// msg contribution for one channel: sigmoid(zg) * softplus(zf)
// STABLE softplus: max(z,0) + ln(1 + e^{-|z|})
__device__ __forceinline__ float gate1(float zg, float zf) {
  float sg = __builtin_amdgcn_rcpf(1.0f + __expf(-zg));
  float sp = fmaxf(zf, 0.0f) + __logf(1.0f + __expf(-fabsf(zf)));
  return sg * sp;
}

// DUAL-STREAM k_agg: each wave interleaves two independent nodes (n, n+10000)
// so stream B's 4 loads fly while stream A computes -> 2x memory-level
// parallelism per wave that the compiler cannot re-serialize (independent
// dependence chains). Uniform branches guard tail mismatch (no divergence).
__global__ __launch_bounds__(256, 6) void k_agg(
    const __hip_bfloat16* __restrict__ Yb, const int* __restrict__ roff,
    const int* __restrict__ src_s, const int* __restrict__ bin_s,
    const __hip_bfloat16* __restrict__ tblL,
    float* __restrict__ xn, __hip_bfloat16* __restrict__ xnb) {
  const int wave = threadIdx.x >> 6, lane = threadIdx.x & 63;
  const int c4 = lane << 2;
  const int w = blockIdx.x * 4 + wave;   // 0..PAIRW-1
  const unsigned short* Ybu = (const unsigned short*)Yb;
  const unsigned short* Tbu = (const unsigned short*)tblL;
  const int HN = NN / 2;

  for (int base = w; base < HN; base += PAIRW) {
    const int nA = base, nB = base + HN;
    const int jbA = __builtin_amdgcn_readfirstlane(roff[nA]);
    const int jeA = __builtin_amdgcn_readfirstlane(roff[nA + 1]);
    const int jbB = __builtin_amdgcn_readfirstlane(roff[nB]);
    const int jeB = __builtin_amdgcn_readfirstlane(roff[nB + 1]);
    const int degA = jeA - jbA, degB = jeB - jbB;
    const int dcapA = degA < 64 ? degA : 64;
    const int dcapB = degB < 64 ? degB : 64;
    const int clA = dcapA > 0 ? dcapA - 1 : 0;
    const int clB = dcapB > 0 ? dcapB - 1 : 0;
    const int dmax = dcapA > dcapB ? dcapA : dcapB;

    const unsigned short* yrA = Ybu + (size_t)nA * 1024;
    const unsigned short* yrB = Ybu + (size_t)nB * 1024;
    f32x4 bgvA = up4(*(const uint2*)(yrA + c4));
    f32x4 bfvA = up4(*(const uint2*)(yrA + c4 + 256));
    f32x4 bgvB = up4(*(const uint2*)(yrB + c4));
    f32x4 bfvB = up4(*(const uint2*)(yrB + c4 + 256));

    int svA = 0, bvA = 0, svB = 0, bvB = 0;
    if (lane < dcapA) { svA = src_s[jbA + lane]; bvA = bin_s[jbA + lane]; }
    if (lane < dcapB) { svB = src_s[jbB + lane]; bvB = bin_s[jbB + lane]; }

    f32x4 m4A = {}, m4B = {};
    for (int i = 0; i < dmax; ++i) {
      const int iA = (i < dcapA) ? i : clA;   // uniform clamp
      const int iB = (i < dcapB) ? i : clB;
      const int snA = __builtin_amdgcn_readlane(svA, iA);
      const int boA = __builtin_amdgcn_readlane(bvA, iA);
      const int snB = __builtin_amdgcn_readlane(svB, iB);
      const int boB = __builtin_amdgcn_readlane(bvB, iB);
      const unsigned short* ysA = Ybu + (size_t)snA * 1024 + 512;
      const unsigned short* ysB = Ybu + (size_t)snB * 1024 + 512;
      uint2 paA = *(const uint2*)(ysA + c4);
      uint2 pfA = *(const uint2*)(ysA + c4 + 256);
      uint2 paB = *(const uint2*)(ysB + c4);
      uint2 pfB = *(const uint2*)(ysB + c4 + 256);
      const unsigned short* tpA = Tbu + boA;
      const unsigned short* tpB = Tbu + boB;
      uint2 tgA = *(const uint2*)(tpA + c4);
      uint2 tfA = *(const uint2*)(tpA + c4 + 256);
      uint2 tgB = *(const uint2*)(tpB + c4);
      uint2 tfB = *(const uint2*)(tpB + c4 + 256);
      if (i < dcapA) {                        // uniform branch
        f32x4 zg = bgvA + up4(paA) + up4(tgA);
        f32x4 zf = bfvA + up4(pfA) + up4(tfA);
        m4A.x += gate1(zg.x, zf.x);
        m4A.y += gate1(zg.y, zf.y);
        m4A.z += gate1(zg.z, zf.z);
        m4A.w += gate1(zg.w, zf.w);
      }
      if (i < dcapB) {
        f32x4 zg = bgvB + up4(paB) + up4(tgB);
        f32x4 zf = bfvB + up4(pfB) + up4(tfB);
        m4B.x += gate1(zg.x, zf.x);
        m4B.y += gate1(zg.y, zf.y);
        m4B.z += gate1(zg.z, zf.z);
        m4B.w += gate1(zg.w, zf.w);
      }
    }
    // rare tails (deg > 64)
    for (int i = 64; i < degA; ++i) {
      int sn = src_s[jbA + i];
      int bo = bin_s[jbA + i];
      const unsigned short* ys = Ybu + (size_t)sn * 1024 + 512;
      uint2 pa = *(const uint2*)(ys + c4);
      uint2 pf = *(const uint2*)(ys + c4 + 256);
      const unsigned short* tp = Tbu + bo;
      uint2 tg = *(const uint2*)(tp + c4);
      uint2 tf = *(const uint2*)(tp + c4 + 256);
      f32x4 zg = bgvA + up4(pa) + up4(tg);
      f32x4 zf = bfvA + up4(pf) + up4(tf);
      m4A.x += gate1(zg.x, zf.x);
      m4A.y += gate1(zg.y, zf.y);
      m4A.z += gate1(zg.z, zf.z);
      m4A.w += gate1(zg.w, zf.w);
    }
    for (int i = 64; i < degB; ++i) {
      int sn = src_s[jbB + i];
      int bo = bin_s[jbB + i];
      const unsigned short* ys = Ybu + (size_t)sn * 1024 + 512;
      uint2 pa = *(const uint2*)(ys + c4);
      uint2 pf = *(const uint2*)(ys + c4 + 256);
      const unsigned short* tp = Tbu + bo;
      uint2 tg = *(const uint2*)(tp + c4);
      uint2 tf = *(const uint2*)(tp + c4 + 256);
      f32x4 zg = bgvB + up4(pa) + up4(tg);
      f32x4 zf = bfvB + up4(pf) + up4(tf);
      m4B.x += gate1(zg.x, zf.x);
      m4B.y += gate1(zg.y, zf.y);
      m4B.z += gate1(zg.z, zf.z);
      m4B.w += gate1(zg.w, zf.w);
    }
    float4 xvA = *(const float4*)(xn + (size_t)nA * EMBD + c4);
    xvA.x += m4A.x; xvA.y += m4A.y; xvA.z += m4A.z; xvA.w += m4A.w;
    *(float4*)(xn + (size_t)nA * EMBD + c4) = xvA;
    __hip_bfloat16* xbpA = xnb + (size_t)nA * EMBD + c4;
    xbpA[0] = __float2bfloat16(xvA.x); xbpA[1] = __float2bfloat16(xvA.y);
    xbpA[2] = __float2bfloat16(xvA.z); xbpA[3] = __float2bfloat16(xvA.w);
    float4 xvB = *(const float4*)(xn + (size_t)nB * EMBD + c4);
    xvB.x += m4B.x; xvB.y += m4B.y; xvB.z += m4B.z; xvB.w += m4B.w;
    *(float4*)(xn + (size_t)nB * EMBD + c4) = xvB;
    __hip_bfloat16* xbpB = xnb + (size_t)nB * EMBD + c4;
    xbpB[0] = __float2bfloat16(xvB.x); xbpB[1] = __float2bfloat16(xvB.y);
    xbpB[2] = __float2bfloat16(xvB.z); xbpB[3] = __float2bfloat16(xvB.w);
  }
}

// ---------------- readout (atomic-free, split partials) ----------------

__global__ __launch_bounds__(256) void k_gsum(
    const float* __restrict__ xn, const int* __restrict__ gi,
    float* __restrict__ gpart, float* __restrict__ gcnt) {
  const int g = blockIdx.x, p = blockIdx.y;
  int lo = 0, hi = NN;
  while (lo < hi) { int m = (lo + hi) >> 1; if (gi[m] < g) lo = m + 1; else hi = m; }
  int lo2 = lo, hi2 = NN;
  while (lo2 < hi2) { int m = (lo2 + hi2) >> 1; if (gi[m] < g + 1) lo2 = m + 1; else hi2 = m; }
  const int cntv = lo2 - lo;
  const int r0 = lo + (cntv * p) / GSPL;
  const int r1 = lo + (cntv * (p + 1)) / GSPL;
  const int c = threadIdx.x;
  float acc = 0.f;
  for (int r = r0; r < r1; ++r) acc += xn[(size_t)r * EMBD + c];
  gpart[((size_t)g * GSPL + p) * EMBD + c] = acc;
  if (p == 0 && c == 0) gcnt[g] = (float)cntv;
}

__global__ __launch_bounds__(256) void k_final(
    const float* __restrict__ gpart, const float* __restrict__ gcnt,
    const float* __restrict__ Wn, const float* __restrict__ bn,
    float* __restrict__ out) {
  __shared__ float s[EMBD];
  const int g = blockIdx.x;
  const int c = threadIdx.x;
  float v = 0.f;
  #pragma unroll
  for (int p = 0; p < GSPL; ++p) v += gpart[((size_t)g * GSPL + p) * EMBD + c];
  s[c] = v;
  __syncthreads();
  if (c < 12) {
    float acc = 0.f;
    for (int k = 0; k < EMBD; ++k) acc += s[k] * Wn[k * 12 + c];
    float cv = gcnt[g];
    out[g * 12 + c] = (cv > 0.f) ? acc / cv + bn[c] : 0.f;
  }
}

// ---------------- launch ----------------

extern "C" void kernel_launch(void* const* d_in, const int* in_sizes, int n_in,
                              void* d_out, int out_size, void* d_ws, size_t ws_size,
                              hipStream_t stream) {
  const int*   x   = (const int*)d_in[0];
  const int*   src = (const int*)d_in[1];
  const int*   dst = (const int*)d_in[2];
  const float* e   = (const float*)d_in[3];
  const int*   gi  = (const int*)d_in[4];
  const float* emb = (const float*)d_in[5];
  const float* We  = (const float*)d_in[6];
  const float* be  = (const float*)d_in[7];
  const float* Wgx = (const float*)d_in[8];
  const float* Wgn = (const float*)d_in[9];
  const float* Wge = (const float*)d_in[10];
  const float* bg  = (const float*)d_in[11];
  const float* Wfx = (const float*)d_in[12];
  const float* Wfn = (const float*)d_in[13];
  const float* Wfe = (const float*)d_in[14];
  const float* bf  = (const float*)d_in[15];
  const float* Wn  = (const float*)d_in[16];
  const float* bn  = (const float*)d_in[17];
  float* out = (float*)d_out;

  char* ws = (char*)d_ws;
  size_t off = 0;
  auto alloc = [&](size_t bytes) {
    void* p = ws + off;
    off += (bytes + 255) & ~(size_t)255;
    return p;
  };
  float*           xn    = (float*)alloc((size_t)NN * EMBD * 4);
  __hip_bfloat16*  xnb   = (__hip_bfloat16*)alloc((size_t)NN * EMBD * 2);
  __hip_bfloat16*  Yb    = (__hip_bfloat16*)alloc((size_t)NN * 1024 * 2);
  int*             bin_s = (int*)alloc((size_t)NE * 4);
  int*             src_s = (int*)alloc((size_t)NE * 4);
  int*             cnt   = (int*)alloc((size_t)NN * 4);
  int*             roff  = (int*)alloc((size_t)(NN + 1) * 4);
  int*             curs  = (int*)alloc((size_t)NN * 4);
  float*           weff  = (float*)alloc((size_t)NL * 2 * RBFD * EMBD * 4);
  float*           beff  = (float*)alloc((size_t)NL * 2 * EMBD * 4);
  __hip_bfloat16*  tbl   = (__hip_bfloat16*)alloc((size_t)NL * (TBINS + 1) * 512 * 2);
  __hip_bfloat16*  WT    = (__hip_bfloat16*)alloc((size_t)NL * 4 * 256 * 256 * 2);
  float*           gpart = (float*)alloc((size_t)NG * GSPL * EMBD * 4);
  float*           gcnt  = (float*)alloc((size_t)NG * 4);
  (void)ws_size; (void)in_sizes; (void)n_in; (void)out_size;

  hipMemsetAsync(cnt, 0, (size_t)NN * 4, stream);

  k_embed<<<(NN * (EMBD / 4) + 255) / 256, 256, 0, stream>>>(x, emb, xn, xnb);
  k_wsmall<<<(NL * 2 * (RBFD + 1) * EMBD + 255) / 256, 256, 0, stream>>>(
      We, be, Wge, bg, Wfe, bf, weff, beff);
  k_table<<<(NL * (TBINS + 1) * 512 + 255) / 256, 256, 0, stream>>>(weff, beff, tbl);
  k_wprep<<<dim3(NL * 4, 16), 256, 0, stream>>>(Wgx, Wfx, Wgn, Wfn, WT);
  k_hist<<<(NE + 255) / 256, 256, 0, stream>>>(dst, cnt);
  k_scan<<<1, 1024, 0, stream>>>(cnt, roff, curs);
  k_scatter<<<(NE + 255) / 256, 256, 0, stream>>>(src, dst, e, curs, src_s, bin_s);

  dim3 mmgrid((NN + 127) / 128, 8);
  for (int l = 0; l < NL; ++l) {
    k_nodemm<<<mmgrid, 256, 0, stream>>>(xnb, WT + (size_t)l * 4 * 65536, Yb);
    k_agg<<<PAIRW / 4, 256, 0, stream>>>(
        Yb, roff, src_s, bin_s, tbl + (size_t)l * (TBINS + 1) * 512, xn, xnb);
  }
  k_gsum<<<dim3(NG, GSPL), 256, 0, stream>>>(xn, gi, gpart, gcnt);
  k_final<<<NG, 256, 0, stream>>>(gpart, gcnt, Wn, bn, out);
}

// Round 21
// 462.727 us; speedup vs baseline: 1.0695x; 1.0695x over previous
//
#include <hip/hip_runtime.h>
#include <hip/hip_bf16.h>
#include <math.h>

#define NN   20000
#define NE   200000
#define NG   128
#define EMBD 256
#define NL   4
#define RBFD 10
#define TBINS 512       // nearest-neighbor bins over d in [0,8]; rows = TBINS+1
#define NWAVE 8192      // persistent waves in k_agg (2048 blocks x 4)
#define GSPL 8

typedef __attribute__((ext_vector_type(8))) short bf16x8;
typedef __attribute__((ext_vector_type(4))) float f32x4;

__device__ __forceinline__ f32x4 up4(uint2 u) {
  f32x4 r;
  r.x = __uint_as_float(u.x << 16);
  r.y = __uint_as_float(u.x & 0xffff0000u);
  r.z = __uint_as_float(u.y << 16);
  r.w = __uint_as_float(u.y & 0xffff0000u);
  return r;
}

__device__ __forceinline__ void gload16(const void* g, void* l) {
  __builtin_amdgcn_global_load_lds(
      (const __attribute__((address_space(1))) void*)g,
      (__attribute__((address_space(3))) void*)l, 16, 0, 0);
}

__device__ __forceinline__ unsigned short bfbits(float v) {
  __hip_bfloat16 h = __float2bfloat16(v);
  return *(unsigned short*)&h;
}

// ---------------- prep kernels ----------------

__global__ void k_embed(const int* __restrict__ x, const float* __restrict__ emb,
                        float* __restrict__ xn, __hip_bfloat16* __restrict__ xnb) {
  int idx = blockIdx.x * blockDim.x + threadIdx.x;   // float4 index
  if (idx >= NN * (EMBD / 4)) return;
  int n  = idx >> 6;
  int c4 = (idx & 63) << 2;
  float4 v = *(const float4*)(emb + (size_t)x[n] * EMBD + c4);
  *(float4*)(xn + (size_t)n * EMBD + c4) = v;
  __hip_bfloat16* xb = xnb + (size_t)n * EMBD + c4;
  xb[0] = __float2bfloat16(v.x); xb[1] = __float2bfloat16(v.y);
  xb[2] = __float2bfloat16(v.z); xb[3] = __float2bfloat16(v.w);
}

// weff[l][gf][k][c] = (We @ W*_e[l])[k][c];  beff[l][gf][c] = be @ W*_e[l] + b*[l]
__global__ void k_wsmall(const float* __restrict__ We, const float* __restrict__ be,
                         const float* __restrict__ Wge, const float* __restrict__ bg,
                         const float* __restrict__ Wfe, const float* __restrict__ bf,
                         float* __restrict__ weff, float* __restrict__ beff) {
  int tid = blockIdx.x * blockDim.x + threadIdx.x;
  const int WPER = RBFD * EMBD;   // 2560
  if (tid < NL * 2 * WPER) {
    int l  = tid / (2 * WPER);
    int r  = tid % (2 * WPER);
    int gf = r / WPER;
    int r2 = r % WPER;
    int k = r2 / EMBD, c = r2 % EMBD;
    const float* W = (gf == 0 ? Wge : Wfe) + (size_t)l * EMBD * EMBD;
    float s = 0.f;
    for (int j = 0; j < EMBD; ++j) s += We[k * EMBD + j] * W[(size_t)j * EMBD + c];
    weff[tid] = s;
  } else {
    int t2 = tid - NL * 2 * WPER;
    if (t2 >= NL * 2 * EMBD) return;
    int l  = t2 / (2 * EMBD);
    int r  = t2 % (2 * EMBD);
    int gf = r / EMBD, c = r % EMBD;
    const float* W = (gf == 0 ? Wge : Wfe) + (size_t)l * EMBD * EMBD;
    const float* b = (gf == 0 ? bg : bf) + (size_t)l * EMBD;
    float s = b[c];
    for (int j = 0; j < EMBD; ++j) s += be[j] * W[(size_t)j * EMBD + c];
    beff[t2] = s;
  }
}

// tbl[l][bin][t] (bf16): t<256 -> zg contribution, t>=256 -> zf; bias folded in
__global__ void k_table(const float* __restrict__ weff, const float* __restrict__ beff,
                        __hip_bfloat16* __restrict__ tbl) {
  int idx = blockIdx.x * blockDim.x + threadIdx.x;
  if (idx >= NL * (TBINS + 1) * 512) return;
  int l = idx / ((TBINS + 1) * 512);
  int r = idx % ((TBINS + 1) * 512);
  int bin = r >> 9;
  int t = r & 511;
  int gf = t >> 8, c = t & 255;
  float d = (float)bin * (8.0f / (float)TBINS);
  const float* w = weff + ((size_t)(l * 2 + gf) * RBFD) * EMBD + c;
  float s = beff[(size_t)(l * 2 + gf) * EMBD + c];
  const float width = 8.0f / 9.0f;
  #pragma unroll
  for (int k = 0; k < RBFD; ++k) {
    float u = (d - (float)k * width) / width;
    s += __expf(-u * u) * w[(size_t)k * EMBD];
  }
  tbl[idx] = __float2bfloat16(s);
}

// WT[l][q][c][k] = W_q[l][k][c] as bf16 (transposed, K-contiguous)
__global__ __launch_bounds__(256) void k_wprep(
    const float* __restrict__ Wgx, const float* __restrict__ Wfx,
    const float* __restrict__ Wgn, const float* __restrict__ Wfn,
    __hip_bfloat16* __restrict__ WT) {
  __shared__ float T[64][65];
  int lq = blockIdx.x; int l = lq >> 2, q = lq & 3;
  const float* W = (q == 0 ? Wgx : q == 1 ? Wfx : q == 2 ? Wgn : Wfn) + (size_t)l * 65536;
  int t = blockIdx.y;
  int k0 = (t & 3) * 64, c0 = (t >> 2) * 64;
  #pragma unroll
  for (int i = 0; i < 16; ++i) {
    int idx = threadIdx.x + i * 256;
    int r = idx >> 6, c = idx & 63;
    T[r][c] = W[(size_t)(k0 + r) * 256 + c0 + c];
  }
  __syncthreads();
  __hip_bfloat16* out = WT + ((size_t)lq * 256) * 256;
  #pragma unroll
  for (int i = 0; i < 16; ++i) {
    int idx = threadIdx.x + i * 256;
    int r = idx >> 6, c = idx & 63;
    out[(size_t)(c0 + r) * 256 + k0 + c] = __float2bfloat16(T[c][r]);
  }
}

// ---------------- CSR build ----------------

__global__ void k_hist(const int* __restrict__ dst, int* __restrict__ cnt) {
  int e = blockIdx.x * blockDim.x + threadIdx.x;
  if (e >= NE) return;
  atomicAdd(&cnt[dst[e]], 1);
}

__global__ __launch_bounds__(1024) void k_scan(const int* __restrict__ cnt,
                                               int* __restrict__ roff,
                                               int* __restrict__ cursor) {
  __shared__ int part[1024];
  const int t = threadIdx.x;
  const int CH = 20;
  int base = t * CH;
  int loc[CH];
  int s = 0;
  #pragma unroll
  for (int i = 0; i < CH; ++i) {
    int idx = base + i;
    int v = (idx < NN) ? cnt[idx] : 0;
    loc[i] = s;
    s += v;
  }
  part[t] = s;
  __syncthreads();
  for (int off = 1; off < 1024; off <<= 1) {
    int v = (t >= off) ? part[t - off] : 0;
    __syncthreads();
    part[t] += v;
    __syncthreads();
  }
  int chunkbase = (t == 0) ? 0 : part[t - 1];
  #pragma unroll
  for (int i = 0; i < CH; ++i) {
    int idx = base + i;
    if (idx < NN) {
      int v = chunkbase + loc[i];
      roff[idx] = v;
      cursor[idx] = v;
    }
  }
  if (t == 1023) roff[NN] = part[1023];
}

// scatter edges dst-sorted; store src and table-row element offset (bin<<9)
__global__ void k_scatter(const int* __restrict__ src, const int* __restrict__ dst,
                          const float* __restrict__ edist,
                          int* __restrict__ cursor,
                          int* __restrict__ src_s, int* __restrict__ bin_s) {
  int e = blockIdx.x * blockDim.x + threadIdx.x;
  if (e >= NE) return;
  int d = dst[e];
  int p = atomicAdd(&cursor[d], 1);
  src_s[p] = src[e];
  int bin = (int)(edist[e] * ((float)TBINS / 8.0f) + 0.5f);
  bin = bin < 0 ? 0 : (bin > TBINS ? TBINS : bin);
  bin_s[p] = bin << 9;
}

// ---------------- per-layer kernels ----------------

// Yb(20000 x 1024, bf16) = xnb @ [Wg_x | Wf_x | Wg_n | Wf_n]  (bf16 MFMA)
// LDS-staged (global_load_lds 16B, swizzled), BK=64, swapped-operand MFMA
__global__ __launch_bounds__(256) void k_nodemm(
    const __hip_bfloat16* __restrict__ xnb, const __hip_bfloat16* __restrict__ WTl,
    __hip_bfloat16* __restrict__ Yb) {
  __shared__ unsigned short As[128 * 64];
  __shared__ unsigned short Bs[128 * 64];
  const int tid = threadIdx.x;
  const int lane = tid & 63;
  const int wave = tid >> 6;
  const int row0 = blockIdx.x << 7;
  const int col0 = blockIdx.y << 7;
  const int q = col0 >> 8;
  const int cb = col0 & 255;
  const unsigned short* xb = (const unsigned short*)xnb;
  const unsigned short* Wb = (const unsigned short*)WTl + ((size_t)q * 256 + cb) * 256;
  const int wnode = (wave >> 1) << 6;
  const int wch   = (wave & 1) << 6;
  f32x4 acc[4][4] = {};

  const int rd0 = (wave << 3) + (lane >> 3);
  const int cd  = lane & 7;

  for (int k0 = 0; k0 < 256; k0 += 64) {
    #pragma unroll
    for (int j = 0; j < 4; ++j) {
      int rd = rd0 + j * 32;
      int cs = cd ^ (rd & 7);
      int ga = row0 + rd; if (ga > NN - 1) ga = NN - 1;
      gload16(xb + (size_t)ga * 256 + k0 + cs * 8,
              (char*)As + (size_t)(j * 256 + wave * 64) * 16);
      gload16(Wb + (size_t)rd * 256 + k0 + cs * 8,
              (char*)Bs + (size_t)(j * 256 + wave * 64) * 16);
    }
    __syncthreads();
    const int rsel = lane & 15, ksl = lane >> 4;
    #pragma unroll
    for (int h = 0; h < 2; ++h) {
      const int c = h * 4 + ksl;
      bf16x8 xa[4], wf[4];
      #pragma unroll
      for (int nn = 0; nn < 4; ++nn) {
        int r = wnode + nn * 16 + rsel;
        xa[nn] = *(const bf16x8*)(&As[r * 64 + (c ^ (r & 7)) * 8]);
      }
      #pragma unroll
      for (int mc = 0; mc < 4; ++mc) {
        int r = wch + mc * 16 + rsel;
        wf[mc] = *(const bf16x8*)(&Bs[r * 64 + (c ^ (r & 7)) * 8]);
      }
      #pragma unroll
      for (int mc = 0; mc < 4; ++mc)
        #pragma unroll
        for (int nn = 0; nn < 4; ++nn)
          acc[mc][nn] = __builtin_amdgcn_mfma_f32_16x16x32_bf16(wf[mc], xa[nn], acc[mc][nn], 0, 0, 0);
    }
    __syncthreads();
  }

  const int nodesel = lane & 15;
  const int chq = (lane >> 4) << 2;
  #pragma unroll
  for (int mc = 0; mc < 4; ++mc) {
    #pragma unroll
    for (int nn = 0; nn < 4; ++nn) {
      int node = row0 + wnode + nn * 16 + nodesel;
      if (node < NN) {
        int ch = col0 + wch + mc * 16 + chq;
        ushort4 pk;
        pk.x = bfbits(acc[mc][nn][0]);
        pk.y = bfbits(acc[mc][nn][1]);
        pk.z = bfbits(acc[mc][nn][2]);
        pk.w = bfbits(acc[mc][nn][3]);
        *(ushort4*)((unsigned short*)Yb + (size_t)node * 1024 + ch) = pk;
      }
    }
  }
}

// msg contribution for one channel: sigmoid(zg) * softplus(zf)
// STABLE softplus: max(z,0) + ln(1 + e^{-|z|})
__device__ __forceinline__ float gate1(float zg, float zf) {
  float sg = __builtin_amdgcn_rcpf(1.0f + __expf(-zg));
  float sp = fmaxf(zf, 0.0f) + __logf(1.0f + __expf(-fabsf(zf)));
  return sg * sp;
}

// grid-stride persistent waves (best-measured form); per edge:
// 2 bf16 gathers + 2 bf16 table loads, uniform SGPR row bases
__global__ __launch_bounds__(256, 8) void k_agg(
    const __hip_bfloat16* __restrict__ Yb, const int* __restrict__ roff,
    const int* __restrict__ src_s, const int* __restrict__ bin_s,
    const __hip_bfloat16* __restrict__ tblL,
    float* __restrict__ xn, __hip_bfloat16* __restrict__ xnb) {
  const int wave = threadIdx.x >> 6, lane = threadIdx.x & 63;
  const int c4 = lane << 2;
  const int wid0 = blockIdx.x * 4 + wave;
  const unsigned short* Ybu = (const unsigned short*)Yb;
  const unsigned short* Tbu = (const unsigned short*)tblL;

  for (int n = wid0; n < NN; n += NWAVE) {
    const int jb   = __builtin_amdgcn_readfirstlane(roff[n]);
    const int jend = __builtin_amdgcn_readfirstlane(roff[n + 1]);
    const int deg = jend - jb;

    const unsigned short* yr = Ybu + (size_t)n * 1024;   // uniform row base
    f32x4 bgv = up4(*(const uint2*)(yr + c4));
    f32x4 bfv = up4(*(const uint2*)(yr + c4 + 256));

    f32x4 m4 = {};
    if (deg > 0) {
      const int dcap = deg < 64 ? deg : 64;
      int sv = 0, bv = 0;
      if (lane < dcap) {
        sv = src_s[jb + lane];
        bv = bin_s[jb + lane];
      }
      for (int i = 0; i < dcap; ++i) {
        int sn = __builtin_amdgcn_readlane(sv, i);     // SGPR
        int bo = __builtin_amdgcn_readlane(bv, i);     // SGPR
        const unsigned short* ys = Ybu + (size_t)sn * 1024 + 512;  // uniform
        uint2 pa = *(const uint2*)(ys + c4);
        uint2 pf = *(const uint2*)(ys + c4 + 256);
        const unsigned short* tp = Tbu + bo;                       // uniform
        uint2 tg = *(const uint2*)(tp + c4);
        uint2 tf = *(const uint2*)(tp + c4 + 256);
        f32x4 zg = bgv + up4(pa) + up4(tg);
        f32x4 zf = bfv + up4(pf) + up4(tf);
        m4.x += gate1(zg.x, zf.x);
        m4.y += gate1(zg.y, zf.y);
        m4.z += gate1(zg.z, zf.z);
        m4.w += gate1(zg.w, zf.w);
      }
      // rare tail (deg > 64)
      for (int i = 64; i < deg; ++i) {
        int sn = src_s[jb + i];
        int bo = bin_s[jb + i];
        const unsigned short* ys = Ybu + (size_t)sn * 1024 + 512;
        uint2 pa = *(const uint2*)(ys + c4);
        uint2 pf = *(const uint2*)(ys + c4 + 256);
        const unsigned short* tp = Tbu + bo;
        uint2 tg = *(const uint2*)(tp + c4);
        uint2 tf = *(const uint2*)(tp + c4 + 256);
        f32x4 zg = bgv + up4(pa) + up4(tg);
        f32x4 zf = bfv + up4(pf) + up4(tf);
        m4.x += gate1(zg.x, zf.x);
        m4.y += gate1(zg.y, zf.y);
        m4.z += gate1(zg.z, zf.z);
        m4.w += gate1(zg.w, zf.w);
      }
    }
    float4 xv = *(const float4*)(xn + (size_t)n * EMBD + c4);
    xv.x += m4.x; xv.y += m4.y; xv.z += m4.z; xv.w += m4.w;
    *(float4*)(xn + (size_t)n * EMBD + c4) = xv;
    __hip_bfloat16* xbp = xnb + (size_t)n * EMBD + c4;
    xbp[0] = __float2bfloat16(xv.x); xbp[1] = __float2bfloat16(xv.y);
    xbp[2] = __float2bfloat16(xv.z); xbp[3] = __float2bfloat16(xv.w);
  }
}

// ---------------- readout (atomic-free, split partials) ----------------

__global__ __launch_bounds__(256) void k_gsum(
    const float* __restrict__ xn, const int* __restrict__ gi,
    float* __restrict__ gpart, float* __restrict__ gcnt) {
  const int g = blockIdx.x, p = blockIdx.y;
  int lo = 0, hi = NN;
  while (lo < hi) { int m = (lo + hi) >> 1; if (gi[m] < g) lo = m + 1; else hi = m; }
  int lo2 = lo, hi2 = NN;
  while (lo2 < hi2) { int m = (lo2 + hi2) >> 1; if (gi[m] < g + 1) lo2 = m + 1; else hi2 = m; }
  const int cntv = lo2 - lo;
  const int r0 = lo + (cntv * p) / GSPL;
  const int r1 = lo + (cntv * (p + 1)) / GSPL;
  const int c = threadIdx.x;
  float acc = 0.f;
  for (int r = r0; r < r1; ++r) acc += xn[(size_t)r * EMBD + c];
  gpart[((size_t)g * GSPL + p) * EMBD + c] = acc;
  if (p == 0 && c == 0) gcnt[g] = (float)cntv;
}

__global__ __launch_bounds__(256) void k_final(
    const float* __restrict__ gpart, const float* __restrict__ gcnt,
    const float* __restrict__ Wn, const float* __restrict__ bn,
    float* __restrict__ out) {
  __shared__ float s[EMBD];
  const int g = blockIdx.x;
  const int c = threadIdx.x;
  float v = 0.f;
  #pragma unroll
  for (int p = 0; p < GSPL; ++p) v += gpart[((size_t)g * GSPL + p) * EMBD + c];
  s[c] = v;
  __syncthreads();
  if (c < 12) {
    float acc = 0.f;
    for (int k = 0; k < EMBD; ++k) acc += s[k] * Wn[k * 12 + c];
    float cv = gcnt[g];
    out[g * 12 + c] = (cv > 0.f) ? acc / cv + bn[c] : 0.f;
  }
}

// ---------------- launch ----------------

extern "C" void kernel_launch(void* const* d_in, const int* in_sizes, int n_in,
                              void* d_out, int out_size, void* d_ws, size_t ws_size,
                              hipStream_t stream) {
  const int*   x   = (const int*)d_in[0];
  const int*   src = (const int*)d_in[1];
  const int*   dst = (const int*)d_in[2];
  const float* e   = (const float*)d_in[3];
  const int*   gi  = (const int*)d_in[4];
  const float* emb = (const float*)d_in[5];
  const float* We  = (const float*)d_in[6];
  const float* be  = (const float*)d_in[7];
  const float* Wgx = (const float*)d_in[8];
  const float* Wgn = (const float*)d_in[9];
  const float* Wge = (const float*)d_in[10];
  const float* bg  = (const float*)d_in[11];
  const float* Wfx = (const float*)d_in[12];
  const float* Wfn = (const float*)d_in[13];
  const float* Wfe = (const float*)d_in[14];
  const float* bf  = (const float*)d_in[15];
  const float* Wn  = (const float*)d_in[16];
  const float* bn  = (const float*)d_in[17];
  float* out = (float*)d_out;

  char* ws = (char*)d_ws;
  size_t off = 0;
  auto alloc = [&](size_t bytes) {
    void* p = ws + off;
    off += (bytes + 255) & ~(size_t)255;
    return p;
  };
  float*           xn    = (float*)alloc((size_t)NN * EMBD * 4);
  __hip_bfloat16*  xnb   = (__hip_bfloat16*)alloc((size_t)NN * EMBD * 2);
  __hip_bfloat16*  Yb    = (__hip_bfloat16*)alloc((size_t)NN * 1024 * 2);
  int*             bin_s = (int*)alloc((size_t)NE * 4);
  int*             src_s = (int*)alloc((size_t)NE * 4);
  int*             cnt   = (int*)alloc((size_t)NN * 4);
  int*             roff  = (int*)alloc((size_t)(NN + 1) * 4);
  int*             curs  = (int*)alloc((size_t)NN * 4);
  float*           weff  = (float*)alloc((size_t)NL * 2 * RBFD * EMBD * 4);
  float*           beff  = (float*)alloc((size_t)NL * 2 * EMBD * 4);
  __hip_bfloat16*  tbl   = (__hip_bfloat16*)alloc((size_t)NL * (TBINS + 1) * 512 * 2);
  __hip_bfloat16*  WT    = (__hip_bfloat16*)alloc((size_t)NL * 4 * 256 * 256 * 2);
  float*           gpart = (float*)alloc((size_t)NG * GSPL * EMBD * 4);
  float*           gcnt  = (float*)alloc((size_t)NG * 4);
  (void)ws_size; (void)in_sizes; (void)n_in; (void)out_size;

  hipMemsetAsync(cnt, 0, (size_t)NN * 4, stream);

  k_embed<<<(NN * (EMBD / 4) + 255) / 256, 256, 0, stream>>>(x, emb, xn, xnb);
  k_wsmall<<<(NL * 2 * (RBFD + 1) * EMBD + 255) / 256, 256, 0, stream>>>(
      We, be, Wge, bg, Wfe, bf, weff, beff);
  k_table<<<(NL * (TBINS + 1) * 512 + 255) / 256, 256, 0, stream>>>(weff, beff, tbl);
  k_wprep<<<dim3(NL * 4, 16), 256, 0, stream>>>(Wgx, Wfx, Wgn, Wfn, WT);
  k_hist<<<(NE + 255) / 256, 256, 0, stream>>>(dst, cnt);
  k_scan<<<1, 1024, 0, stream>>>(cnt, roff, curs);
  k_scatter<<<(NE + 255) / 256, 256, 0, stream>>>(src, dst, e, curs, src_s, bin_s);

  dim3 mmgrid((NN + 127) / 128, 8);
  for (int l = 0; l < NL; ++l) {
    k_nodemm<<<mmgrid, 256, 0, stream>>>(xnb, WT + (size_t)l * 4 * 65536, Yb);
    k_agg<<<NWAVE / 4, 256, 0, stream>>>(
        Yb, roff, src_s, bin_s, tbl + (size_t)l * (TBINS + 1) * 512, xn, xnb);
  }
  k_gsum<<<dim3(NG, GSPL), 256, 0, stream>>>(xn, gi, gpart, gcnt);
  k_final<<<NG, 256, 0, stream>>>(gpart, gcnt, Wn, bn, out);
}